// Round 11
// baseline (340.179 us; speedup 1.0000x reference)
//
#include <hip/hip_runtime.h>
#include <hip/hip_bf16.h>
#include <math.h>
#include <stdint.h>

// Problem constants
#define E_ 8
#define R_ 32
#define D_ 1024
#define H_ 4096
#define NTOK 4096          // B*S
#define M_MAX 5120         // padded-token capacity (40 tiles of 128)
#define TILES_MAX 40
#define SCALING 0.03125f   // 1/R

typedef __attribute__((ext_vector_type(8))) __bf16 bf16x8;
typedef __attribute__((ext_vector_type(8))) unsigned short ushort8;
typedef __attribute__((ext_vector_type(4))) float floatx4;

__device__ __forceinline__ float b2f(unsigned short u) {
    union { unsigned int i; float f; } v; v.i = ((unsigned int)u) << 16; return v.f;
}
__device__ __forceinline__ unsigned short f2b(float f) {
    union { float f; unsigned int i; } v; v.f = f;
    unsigned int x = v.i;
    x += 0x7fffu + ((x >> 16) & 1u);   // round-to-nearest-even
    return (unsigned short)(x >> 16);
}
// tanh-form GELU (max |err| vs exact ~1.5e-4; propagated ~1e-4 — noise).
__device__ __forceinline__ float gelu_fast(float v) {
    float u = v * (0.7978845608028654f + 0.0356774080857f * v * v);
    float t = __expf(-2.f * fabsf(u));
    float th = (1.f - t) * __builtin_amdgcn_rcpf(1.f + t);
    th = (u >= 0.f) ? th : -th;
    return 0.5f * v * (1.f + th);
}

#define GLOAD_LDS16(g, l) __builtin_amdgcn_global_load_lds( \
    (const __attribute__((address_space(1))) void*)(g),     \
    (__attribute__((address_space(3))) void*)(l), 16, 0, 0)

// ---------------------------------------------------------------------------
// Kernel 0: fused prep = weight fp32->bf16 conversion (blocks 0..5375) +
// router (blocks 5376..6399, one wave per token, fp32, fp32 outputs).
// ---------------------------------------------------------------------------
__global__ __launch_bounds__(256) void k_prep(
    const float* __restrict__ w1, const float* __restrict__ w2,
    const float* __restrict__ Ad, const float* __restrict__ Bd,
    const float* __restrict__ Au, const float* __restrict__ Bu,
    unsigned short* __restrict__ w1b, unsigned short* __restrict__ w2b,
    unsigned short* __restrict__ Adb, unsigned short* __restrict__ Bdb,
    unsigned short* __restrict__ Aub, unsigned short* __restrict__ Bub,
    const float* __restrict__ x, const float* __restrict__ rw,
    const float* __restrict__ rb,
    float* __restrict__ out, int* __restrict__ idx)
{
    if (blockIdx.x < 5376) {
        long g = ((long)blockIdx.x * 256 + threadIdx.x) * 8;
        const float* src; unsigned short* dst; long off;
        if      (g <  4194304L) { src = w1; dst = w1b; off = 0; }
        else if (g <  8388608L) { src = w2; dst = w2b; off = 4194304L; }
        else if (g <  8650752L) { src = Ad; dst = Adb; off = 8388608L; }
        else if (g <  9699328L) { src = Bd; dst = Bdb; off = 8650752L; }
        else if (g < 10747904L) { src = Au; dst = Aub; off = 9699328L; }
        else                    { src = Bu; dst = Bub; off = 10747904L; }
        long i = g - off;
        float4 a = *(const float4*)(src + i);
        float4 b = *(const float4*)(src + i + 4);
        ushort8 o;
        o[0] = f2b(a.x); o[1] = f2b(a.y); o[2] = f2b(a.z); o[3] = f2b(a.w);
        o[4] = f2b(b.x); o[5] = f2b(b.y); o[6] = f2b(b.z); o[7] = f2b(b.w);
        *(ushort8*)(dst + i) = o;
        return;
    }
    const int wave = threadIdx.x >> 6, lane = threadIdx.x & 63;
    const int t = (blockIdx.x - 5376) * 4 + wave;
    const float4* xr = (const float4*)(x + (size_t)t * D_);
    float4 xv[4];
#pragma unroll
    for (int s = 0; s < 4; ++s) xv[s] = xr[lane + 64 * s];
    float acc[E_];
#pragma unroll
    for (int e = 0; e < E_; ++e) {
        const float4* wr = (const float4*)(rw + (size_t)e * D_);
        float s = 0.f;
#pragma unroll
        for (int u = 0; u < 4; ++u) {
            float4 wv = wr[lane + 64 * u];
            s += xv[u].x * wv.x + xv[u].y * wv.y + xv[u].z * wv.z + xv[u].w * wv.w;
        }
        acc[e] = s;
    }
#pragma unroll
    for (int e = 0; e < E_; ++e) {
#pragma unroll
        for (int m = 32; m > 0; m >>= 1) acc[e] += __shfl_xor(acc[e], m, 64);
        acc[e] += rb[e];
    }
    int best = 0;
#pragma unroll
    for (int e = 1; e < E_; ++e) if (acc[e] > acc[best]) best = e;   // first-max (np.argmax)
    const float mx = acc[best];
    float pr[E_]; float se = 0.f;
#pragma unroll
    for (int e = 0; e < E_; ++e) { pr[e] = expf(acc[e] - mx); se += pr[e]; }
    const float inv = 1.f / se;
    if (lane < E_) {
        float r = pr[lane] * inv;
        out[(size_t)NTOK * D_ + (size_t)t * E_ + lane] = r;
        float maskv = (lane == best) ? 1.f : 0.f;
        out[(size_t)NTOK * D_ + (size_t)NTOK * E_ + (size_t)t * E_ + lane] = (maskv - r) + r;
    }
    if (lane == 0) idx[t] = best;
}

// ---------------------------------------------------------------------------
// Kernel 2: scan (1 block). Deterministic expert-sorted permutation, segments
// padded to multiples of 128 so every GEMM tile has a uniform expert.
// ---------------------------------------------------------------------------
__global__ __launch_bounds__(256) void k_scan(
    const int* __restrict__ idx, int* __restrict__ hdr,
    int* __restrict__ tile_e, int* __restrict__ gather)
{
    __shared__ int cnt[256][E_];
    __shared__ int tot[E_], base[E_];
    const int tid = threadIdx.x;
    for (int m = tid; m < M_MAX; m += 256) gather[m] = -1;
    int c[E_];
#pragma unroll
    for (int e = 0; e < E_; ++e) c[e] = 0;
    for (int t = tid * 16; t < tid * 16 + 16; ++t) c[idx[t] & 7]++;
#pragma unroll
    for (int e = 0; e < E_; ++e) cnt[tid][e] = c[e];
    __syncthreads();
    if (tid < E_) {
        int run = 0;
        for (int i = 0; i < 256; ++i) { int v = cnt[i][tid]; cnt[i][tid] = run; run += v; }
        tot[tid] = run;
    }
    __syncthreads();
    if (tid == 0) {
        int b = 0, tp = 0;
        for (int e = 0; e < E_; ++e) {
            base[e] = b;
            int nt = (tot[e] + 127) >> 7;
            for (int k = 0; k < nt; ++k) tile_e[tp++] = e;
            b += nt << 7;
        }
        hdr[0] = b;       // M_pad
        hdr[1] = tp;      // n_tiles
        for (int k = tp; k < TILES_MAX; ++k) tile_e[k] = 0;
    }
    __syncthreads();
    int p[E_];
#pragma unroll
    for (int e = 0; e < E_; ++e) p[e] = base[e] + cnt[tid][e];
    for (int t = tid * 16; t < tid * 16 + 16; ++t) { int e = idx[t] & 7; gather[p[e]++] = t; }
}

// ---------------------------------------------------------------------------
// Kernel 3: gather + fused LoRA-A-down. One block (128 thr) per sorted row m:
// (a) gather x row -> bf16 xg (zeros for pads);
// (b) hs[r] = SCALING*(x_t . Adb[e,r,:] + Ab[e,r]) -> bf16 hsb  (pads: dot=0).
// Adb is 512 KB total -> L2-resident across the grid.
// ---------------------------------------------------------------------------
__global__ __launch_bounds__(128) void k_gather(
    const float* __restrict__ x, const unsigned short* __restrict__ Adb,
    const float* __restrict__ Abd,
    const int* __restrict__ gather, const int* __restrict__ tile_e,
    unsigned short* __restrict__ xg, unsigned short* __restrict__ hsb)
{
    const int m = blockIdx.x, tid = threadIdx.x;
    const int t = gather[m];
    const int e = tile_e[m >> 7] & 7;
    const bool valid = (unsigned)t < (unsigned)NTOK;
    // (a) gather row
    {
        ushort8* dst = (ushort8*)(xg + (size_t)m * D_);
        ushort8 o;
        if (valid) {
            const float4* src = (const float4*)(x + (size_t)t * D_);
            float4 a = src[tid * 2], b = src[tid * 2 + 1];
            o[0] = f2b(a.x); o[1] = f2b(a.y); o[2] = f2b(a.z); o[3] = f2b(a.w);
            o[4] = f2b(b.x); o[5] = f2b(b.y); o[6] = f2b(b.z); o[7] = f2b(b.w);
        } else {
            o = (ushort8)(0);
        }
        dst[tid] = o;
    }
    // (b) A-stage: rank r = tid&31, chunk c = tid>>5 (256 elems each)
    const int r = tid & 31, c = tid >> 5;
    float s = 0.f;
    if (valid) {
        const float4* xv = (const float4*)(x + (size_t)t * D_ + c * 256);
        const ushort8* av = (const ushort8*)(Adb + ((size_t)e * 32 + r) * D_ + c * 256);
#pragma unroll 4
        for (int i = 0; i < 32; ++i) {
            float4 xa = xv[i * 2], xb = xv[i * 2 + 1];
            ushort8 a8 = av[i];
            s += xa.x * b2f(a8[0]) + xa.y * b2f(a8[1]) + xa.z * b2f(a8[2]) + xa.w * b2f(a8[3])
               + xb.x * b2f(a8[4]) + xb.y * b2f(a8[5]) + xb.z * b2f(a8[6]) + xb.w * b2f(a8[7]);
        }
    }
    __shared__ float part[32][4];
    part[r][c] = s;
    __syncthreads();
    if (tid < 32) {
        float ss = part[tid][0] + part[tid][1] + part[tid][2] + part[tid][3];
        hsb[(size_t)m * 32 + tid] = f2b(SCALING * (ss + Abd[e * 32 + tid]));
    }
}

// ---------------------------------------------------------------------------
// Kernel 4: LoRA A-stage (up), single pass MFMA. Block = 32 m-rows x 32 ranks;
// 4 waves split K, LDS-reduce, add Ab, pre-scale, write bf16. grid=(4,TILES).
// ---------------------------------------------------------------------------
__global__ __launch_bounds__(256) void k_lora_a2(
    const unsigned short* __restrict__ A,    // [M_MAX, Ktot] bf16 (a_g)
    const unsigned short* __restrict__ W,    // [E, 32, Ktot] bf16
    const float* __restrict__ Ab,            // [E, 32] fp32
    const int* __restrict__ hdr, const int* __restrict__ tile_e,
    unsigned short* __restrict__ outb,       // [M_MAX, 32] bf16 pre-scaled
    int Ktot)
{
    const int mtile = blockIdx.y;
    int ntiles = hdr[1]; if (ntiles > TILES_MAX) ntiles = TILES_MAX;
    if (mtile >= ntiles) return;
    const int e = tile_e[mtile] & 7;
    const int m0 = mtile * 128 + blockIdx.x * 32;
    const int wave = threadIdx.x >> 6, lane = threadIdx.x & 63;
    const int q = lane >> 4, l16 = lane & 15;
    const int Ks = Ktot >> 2;
    const int kbase = wave * Ks;
    const floatx4 z4 = {0.f, 0.f, 0.f, 0.f};
    floatx4 acc[2][2] = {{z4, z4}, {z4, z4}};
    const bf16x8* A0 = (const bf16x8*)(A + (size_t)(m0 + l16) * Ktot);
    const bf16x8* A1 = (const bf16x8*)(A + (size_t)(m0 + 16 + l16) * Ktot);
    const bf16x8* W0 = (const bf16x8*)(W + ((size_t)e * 32 + l16) * Ktot);
    const bf16x8* W1 = (const bf16x8*)(W + ((size_t)e * 32 + 16 + l16) * Ktot);
    for (int k = kbase; k < kbase + Ks; k += 32) {
        int u = (k >> 3) + q;
        bf16x8 a0 = A0[u], a1 = A1[u];
        bf16x8 b0 = W0[u], b1 = W1[u];
        acc[0][0] = __builtin_amdgcn_mfma_f32_16x16x32_bf16(a0, b0, acc[0][0], 0, 0, 0);
        acc[0][1] = __builtin_amdgcn_mfma_f32_16x16x32_bf16(a0, b1, acc[0][1], 0, 0, 0);
        acc[1][0] = __builtin_amdgcn_mfma_f32_16x16x32_bf16(a1, b0, acc[1][0], 0, 0, 0);
        acc[1][1] = __builtin_amdgcn_mfma_f32_16x16x32_bf16(a1, b1, acc[1][1], 0, 0, 0);
    }
    __shared__ float red[4][32][32];
#pragma unroll
    for (int mi = 0; mi < 2; ++mi)
#pragma unroll
        for (int ni = 0; ni < 2; ++ni)
#pragma unroll
            for (int r = 0; r < 4; ++r)
                red[wave][mi * 16 + q * 4 + r][ni * 16 + l16] = acc[mi][ni][r];
    __syncthreads();
    for (int i = threadIdx.x; i < 1024; i += 256) {
        int lr = i >> 5, c = i & 31;
        float s = red[0][lr][c] + red[1][lr][c] + red[2][lr][c] + red[3][lr][c];
        outb[(size_t)(m0 + lr) * 32 + c] = f2b(SCALING * (s + Ab[e * 32 + c]));
    }
}

// ---------------------------------------------------------------------------
// Main GEMM: 128m x BN n tile, BK=64, global_load_lds w16 DMA into
// XOR-swizzled LDS, mfma_f32_16x16x32_bf16, fused LoRA-B + fp32 bias.
// fc1 (BN=128): tanh-GELU -> bf16 a_g. fc2 (BN=64): fp32 scatter to d_out.
// ---------------------------------------------------------------------------
template <int KTOT, int BN, bool IS_FC1>
__global__ __launch_bounds__(256) void k_mlp(
    const unsigned short* __restrict__ Amat,   // [M_MAX, KTOT] bf16
    const unsigned short* __restrict__ Wmat,   // [NOUT, KTOT] bf16 (NT layout)
    const float* __restrict__ bias,            // [NOUT] fp32
    const unsigned short* __restrict__ lora_h, // [M_MAX, 32] pre-scaled bf16
    const unsigned short* __restrict__ lora_B, // [E, NOUT, 32] bf16
    const float* __restrict__ lora_b,          // [E, NOUT] fp32
    const int* __restrict__ hdr, const int* __restrict__ tile_e,
    const int* __restrict__ gather,
    unsigned short* __restrict__ outb,         // fc1: a_g bf16
    float* __restrict__ outf,                  // fc2: d_out fp32
    int NOUT)
{
    constexpr int NI = BN / 32;                // n-subtiles per wave
    const int mtile = blockIdx.y;
    int ntiles = hdr[1]; if (ntiles > TILES_MAX) ntiles = TILES_MAX;
    if (mtile >= ntiles) return;
    const int e = tile_e[mtile] & 7;
    const int h0 = blockIdx.x * BN;
    const int m0 = mtile * 128;
    __shared__ bf16x8 As[1024];                // 128 rows x 8 units
    __shared__ bf16x8 Bs[BN * 8];              // BN rows x 8 units
    const int tid = threadIdx.x;
    const int lane = tid & 63;
    const int q = lane >> 4, l16 = lane & 15;
    const int wave = tid >> 6;
    const int wm = wave & 1, wn = wave >> 1;
    const floatx4 z4 = {0.f, 0.f, 0.f, 0.f};
    floatx4 acc[4][NI];
#pragma unroll
    for (int mi = 0; mi < 4; ++mi)
#pragma unroll
        for (int ni = 0; ni < NI; ++ni) acc[mi][ni] = z4;

    const unsigned short* Abase = Amat + (size_t)m0 * KTOT;
    const unsigned short* Bbase = Wmat + (size_t)h0 * KTOT;

    for (int k0 = 0; k0 < KTOT; k0 += 64) {
#pragma unroll
        for (int rnd = 0; rnd < 4; ++rnd) {
            int s = rnd * 256 + tid;
            int row = s >> 3;
            int jj = (s & 7) ^ (row & 7);
            GLOAD_LDS16(Abase + (size_t)row * KTOT + k0 + jj * 8, As + rnd * 256 + wave * 64);
        }
#pragma unroll
        for (int rnd = 0; rnd < BN / 32; ++rnd) {
            int s = rnd * 256 + tid;
            int row = s >> 3;
            int jj = (s & 7) ^ (row & 7);
            GLOAD_LDS16(Bbase + (size_t)row * KTOT + k0 + jj * 8, Bs + rnd * 256 + wave * 64);
        }
        __syncthreads();
#pragma unroll
        for (int ka = 0; ka < 2; ++ka) {
            bf16x8 af[4], bfr[NI];
#pragma unroll
            for (int mi = 0; mi < 4; ++mi) {
                int row = wm * 64 + mi * 16 + l16;
                af[mi] = As[row * 8 + ((ka * 4 + q) ^ (row & 7))];
            }
#pragma unroll
            for (int ni = 0; ni < NI; ++ni) {
                int row = wn * (BN / 2) + ni * 16 + l16;
                bfr[ni] = Bs[row * 8 + ((ka * 4 + q) ^ (row & 7))];
            }
#pragma unroll
            for (int mi = 0; mi < 4; ++mi)
#pragma unroll
                for (int ni = 0; ni < NI; ++ni)
                    acc[mi][ni] = __builtin_amdgcn_mfma_f32_16x16x32_bf16(af[mi], bfr[ni], acc[mi][ni], 0, 0, 0);
        }
        __syncthreads();
    }

    // Fused LoRA-B: one K=32 MFMA per subtile.
    {
        bf16x8 a2[4], b2[NI];
#pragma unroll
        for (int mi = 0; mi < 4; ++mi)
            a2[mi] = *(const bf16x8*)(lora_h + (size_t)(m0 + wm * 64 + mi * 16 + l16) * 32 + q * 8);
#pragma unroll
        for (int ni = 0; ni < NI; ++ni)
            b2[ni] = *(const bf16x8*)(lora_B + ((size_t)e * NOUT + h0 + wn * (BN / 2) + ni * 16 + l16) * 32 + q * 8);
#pragma unroll
        for (int mi = 0; mi < 4; ++mi)
#pragma unroll
            for (int ni = 0; ni < NI; ++ni)
                acc[mi][ni] = __builtin_amdgcn_mfma_f32_16x16x32_bf16(a2[mi], b2[ni], acc[mi][ni], 0, 0, 0);
    }

#pragma unroll
    for (int ni = 0; ni < NI; ++ni) {
        int gh = h0 + wn * (BN / 2) + ni * 16 + l16;
        float bv = bias[gh] + SCALING * lora_b[e * NOUT + gh];
#pragma unroll
        for (int mi = 0; mi < 4; ++mi) {
#pragma unroll
            for (int r = 0; r < 4; ++r) {
                int gm = m0 + wm * 64 + mi * 16 + q * 4 + r;
                float v = acc[mi][ni][r] + bv;
                if (IS_FC1) {
                    outb[(size_t)gm * NOUT + gh] = f2b(gelu_fast(v));
                } else {
                    int t = gather[gm];
                    if ((unsigned)t < (unsigned)NTOK) outf[(size_t)t * NOUT + gh] = v;
                }
            }
        }
    }
}

// ---------------------------------------------------------------------------
// Workspace layout (bytes).
// ---------------------------------------------------------------------------
#define OFF_IDX      0u
#define OFF_HDR      16384u
#define OFF_TILE     16640u
#define OFF_GATHER   16896u        // ends 37376
#define OFF_XG       37376u        // 10,485,760
#define OFF_W1B      10523136u     // 8,388,608
#define OFF_ADB      18911744u     // 524,288
#define OFF_BDB      19436032u     // 2,097,152
#define OFF_HSB      21533184u     // 327,680 -> ends 21,860,864
#define OFF_AG       21860864u     // 41,943,040
#define OFF_HUB      63803904u     // 327,680
#define OFF_W2B      64131584u     // 8,388,608
#define OFF_AUB      72520192u     // 2,097,152
#define OFF_BUB      74617344u     // 524,288
#define WS_NEEDED    75141632u

extern "C" void kernel_launch(void* const* d_in, const int* in_sizes, int n_in,
                              void* d_out, int out_size, void* d_ws, size_t ws_size,
                              hipStream_t stream)
{
    (void)out_size;
    if (ws_size < (size_t)WS_NEEDED) return;
    if (n_in < 15 || in_sizes[0] != NTOK * D_ || in_sizes[3] != H_ * D_ ||
        in_sizes[5] != D_ * H_ || in_sizes[9] != E_ * H_ * R_) return;

    const float* x   = (const float*)d_in[0];
    const float* rw  = (const float*)d_in[1];
    const float* rb  = (const float*)d_in[2];
    const float* w1  = (const float*)d_in[3];
    const float* b1  = (const float*)d_in[4];
    const float* w2  = (const float*)d_in[5];
    const float* b2  = (const float*)d_in[6];
    const float* Ad  = (const float*)d_in[7];
    const float* Abd = (const float*)d_in[8];
    const float* Bd  = (const float*)d_in[9];
    const float* Bbd = (const float*)d_in[10];
    const float* Au  = (const float*)d_in[11];
    const float* Abu = (const float*)d_in[12];
    const float* Bu  = (const float*)d_in[13];
    const float* Bbu = (const float*)d_in[14];
    float* out = (float*)d_out;
    char* ws = (char*)d_ws;

    int* idx            = (int*)(ws + OFF_IDX);
    int* hdr            = (int*)(ws + OFF_HDR);
    int* tile_e         = (int*)(ws + OFF_TILE);
    int* gather         = (int*)(ws + OFF_GATHER);
    unsigned short* xg  = (unsigned short*)(ws + OFF_XG);
    unsigned short* hsb = (unsigned short*)(ws + OFF_HSB);
    unsigned short* ag  = (unsigned short*)(ws + OFF_AG);
    unsigned short* hub = (unsigned short*)(ws + OFF_HUB);
    unsigned short* w1b = (unsigned short*)(ws + OFF_W1B);
    unsigned short* w2b = (unsigned short*)(ws + OFF_W2B);
    unsigned short* Adb = (unsigned short*)(ws + OFF_ADB);
    unsigned short* Bdb = (unsigned short*)(ws + OFF_BDB);
    unsigned short* Aub = (unsigned short*)(ws + OFF_AUB);
    unsigned short* Bub = (unsigned short*)(ws + OFF_BUB);

    // prep = weight cvt (5376 blocks) + router (1024 blocks)
    k_prep<<<6400, 256, 0, stream>>>(w1, w2, Ad, Bd, Au, Bu,
                                     w1b, w2b, Adb, Bdb, Aub, Bub,
                                     x, rw, rb, out, idx);
    k_scan<<<1, 256, 0, stream>>>(idx, hdr, tile_e, gather);
    k_gather<<<M_MAX, 128, 0, stream>>>(x, Adb, Abd, gather, tile_e, xg, hsb);
    k_mlp<D_, 128, true><<<dim3(H_ / 128, TILES_MAX), 256, 0, stream>>>(
        xg, w1b, b1, hsb, Bdb, Bbd, hdr, tile_e, gather, ag, nullptr, H_);
    k_lora_a2<<<dim3(4, TILES_MAX), 256, 0, stream>>>(ag, Aub, Abu, hdr, tile_e, hub, H_);
    k_mlp<H_, 64, false><<<dim3(D_ / 64, TILES_MAX), 256, 0, stream>>>(
        ag, w2b, b2, hub, Bub, Bbu, hdr, tile_e, gather, nullptr, out, D_);
}